// Round 3
// baseline (150.350 us; speedup 1.0000x reference)
//
#include <hip/hip_runtime.h>
#include <stdint.h>

#define BB 256
#define DD 128
#define KK 32
#define MM1 64
#define MM2 32

typedef __attribute__((ext_vector_type(8))) short bf16x8;
typedef __attribute__((ext_vector_type(4))) float f32x4;

#define LOG2E 1.44269504088896f

// ---- ws layout (bytes) ----
// 0       reconT  f32 [32][256]   (vae)        32KB
// 32768   betaT   f32 [32][256]   (prep)       32KB
// 65536   xbf     bf16[256][128]  (prep)       64KB
// 131072  lc1T    bf16[1024][64]  (prep) rows cp=k*32+n, cols m   128KB
// 262144  lc1bs   f32 [32][32]  = -lc1b*LOG2E  4KB
// 266240  lc2bq   f32 [32]      = 0.25*lc2b
// 270336  b1s     f32 [128][64] = -(b1p-b1n)*LOG2E   32KB
// 303104  w1bf    bf16[128][64][128]           2MB

__device__ __forceinline__ short f2b(float f) {
  uint32_t u = __builtin_bit_cast(uint32_t, f);
  u += 0x7FFFu + ((u >> 16) & 1u);          // RNE to bf16
  return (short)(u >> 16);
}
__device__ __forceinline__ float sigm_pre(float acc, float cpre) {
  // sigmoid(acc + bias) with cpre = -bias*LOG2E
  return __builtin_amdgcn_rcpf(
      1.0f + __builtin_amdgcn_exp2f(fmaf(acc, -LOG2E, cpre)));
}

// ---------------------------------------------------------------------------
// Combo kernel: blocks 0..1023 = prep (dtype conversion / transposes),
//               blocks 1024..1279 = VAE (one block per sample b).
// ---------------------------------------------------------------------------
__global__ __launch_bounds__(256) void combo_kernel(
    const float* __restrict__ x, const float* __restrict__ W1p,
    const float* __restrict__ W1n, const float* __restrict__ b1p,
    const float* __restrict__ b1n, const float* __restrict__ lc1w,
    const float* __restrict__ lc1b, const float* __restrict__ lc2b,
    const float* __restrict__ betaw,
    const float* __restrict__ enc1w, const float* __restrict__ enc1b,
    const float* __restrict__ enc2w, const float* __restrict__ enc2b,
    const float* __restrict__ muw,  const float* __restrict__ mub,
    const float* __restrict__ lvw,  const float* __restrict__ lvb,
    const float* __restrict__ dec1w, const float* __restrict__ dec1b,
    const float* __restrict__ dec2w, const float* __restrict__ dec2b,
    const float* __restrict__ dec3w, const float* __restrict__ dec3b,
    const float* __restrict__ eps,
    char* __restrict__ ws, float* __restrict__ mu_out,
    float* __restrict__ lv_out)
{
  const int bx = blockIdx.x;
  if (bx < 1024) {
    // ---------------- prep ----------------
    const int tid = bx * 256 + threadIdx.x;   // 0..262143
    { // W1bf = bf16(W1p - W1n), linear [d][m][i], 262144 float4
      float4 a = ((const float4*)W1p)[tid];
      float4 b = ((const float4*)W1n)[tid];
      short4 s;
      s.x = f2b(a.x - b.x); s.y = f2b(a.y - b.y);
      s.z = f2b(a.z - b.z); s.w = f2b(a.w - b.w);
      ((short4*)(ws + 303104))[tid] = s;
    }
    if (tid < 8192) { // xbf
      float4 v = ((const float4*)x)[tid];
      short4 s;
      s.x = f2b(v.x); s.y = f2b(v.y); s.z = f2b(v.z); s.w = f2b(v.w);
      ((short4*)(ws + 65536))[tid] = s;
    }
    if (tid < 65536) { // lc1T[(k*32+n)*64 + m] = lc1w[k][m][n]
      int k = tid >> 11, n = (tid >> 6) & 31, m = tid & 63;
      ((short*)(ws + 131072))[tid] = f2b(lc1w[k * 2048 + m * 32 + n]);
    }
    if (tid < 8192) { // betaT[k*256 + b]
      ((float*)(ws + 32768))[tid] = betaw[(tid & 255) * 32 + (tid >> 8)];
    }
    if (tid < 1024) { ((float*)(ws + 262144))[tid] = -lc1b[tid] * LOG2E; }
    if (tid < 32) { ((float*)(ws + 266240))[tid] = 0.25f * lc2b[tid]; }
    if (tid < 8192) { // b1s
      ((float*)(ws + 270336))[tid] = -(b1p[tid] - b1n[tid]) * LOG2E;
    }
    return;
  }

  // ---------------- VAE (one block per sample) ----------------
  const int b = bx - 1024, t = threadIdx.x;
  float* reconT = (float*)ws;
  __shared__ float bw[KK], e1[128], e2[64], zz[32], d1s[64], d2s[128];
  if (t < KK) bw[t] = betaw[b * KK + t];
  __syncthreads();
  if (t < 128) { // enc1: K->128
    float a0 = enc1b[t], a1 = 0.f;
    #pragma unroll
    for (int k = 0; k < KK; k += 2) {
      a0 = fmaf(bw[k], enc1w[k * 128 + t], a0);
      a1 = fmaf(bw[k + 1], enc1w[(k + 1) * 128 + t], a1);
    }
    e1[t] = fmaxf(a0 + a1, 0.f);
  }
  __syncthreads();
  if (t < 64) { // enc2: 128->64
    float a0 = enc2b[t], a1 = 0.f, a2 = 0.f, a3 = 0.f;
    #pragma unroll 8
    for (int h = 0; h < 128; h += 4) {
      a0 = fmaf(e1[h], enc2w[h * 64 + t], a0);
      a1 = fmaf(e1[h + 1], enc2w[(h + 1) * 64 + t], a1);
      a2 = fmaf(e1[h + 2], enc2w[(h + 2) * 64 + t], a2);
      a3 = fmaf(e1[h + 3], enc2w[(h + 3) * 64 + t], a3);
    }
    e2[t] = fmaxf((a0 + a1) + (a2 + a3), 0.f);
  }
  __syncthreads();
  if (t < 32) { // mu / logvar / z
    float m0 = mub[t], m1 = 0.f, l0 = lvb[t], l1 = 0.f;
    #pragma unroll 8
    for (int h = 0; h < 64; h += 2) {
      float ea = e2[h], eb = e2[h + 1];
      m0 = fmaf(ea, muw[h * 32 + t], m0);
      m1 = fmaf(eb, muw[(h + 1) * 32 + t], m1);
      l0 = fmaf(ea, lvw[h * 32 + t], l0);
      l1 = fmaf(eb, lvw[(h + 1) * 32 + t], l1);
    }
    float m = m0 + m1, l = l0 + l1;
    mu_out[b * 32 + t] = m;
    lv_out[b * 32 + t] = l;
    zz[t] = fmaf(eps[b * 32 + t], __expf(0.5f * l), m);
  }
  __syncthreads();
  if (t < 64) { // dec1: 32->64
    float a0 = dec1b[t], a1 = 0.f;
    #pragma unroll
    for (int l = 0; l < 32; l += 2) {
      a0 = fmaf(zz[l], dec1w[l * 64 + t], a0);
      a1 = fmaf(zz[l + 1], dec1w[(l + 1) * 64 + t], a1);
    }
    d1s[t] = fmaxf(a0 + a1, 0.f);
  }
  __syncthreads();
  if (t < 128) { // dec2: 64->128
    float a0 = dec2b[t], a1 = 0.f, a2 = 0.f, a3 = 0.f;
    #pragma unroll 8
    for (int h = 0; h < 64; h += 4) {
      a0 = fmaf(d1s[h], dec2w[h * 128 + t], a0);
      a1 = fmaf(d1s[h + 1], dec2w[(h + 1) * 128 + t], a1);
      a2 = fmaf(d1s[h + 2], dec2w[(h + 2) * 128 + t], a2);
      a3 = fmaf(d1s[h + 3], dec2w[(h + 3) * 128 + t], a3);
    }
    d2s[t] = fmaxf((a0 + a1) + (a2 + a3), 0.f);
  }
  __syncthreads();
  if (t < 32) { // dec3: 128->K, transposed write
    float a0 = dec3b[t], a1 = 0.f, a2 = 0.f, a3 = 0.f;
    #pragma unroll 8
    for (int h = 0; h < 128; h += 4) {
      a0 = fmaf(d2s[h], dec3w[h * 32 + t], a0);
      a1 = fmaf(d2s[h + 1], dec3w[(h + 1) * 32 + t], a1);
      a2 = fmaf(d2s[h + 2], dec3w[(h + 2) * 32 + t], a2);
      a3 = fmaf(d2s[h + 3], dec3w[(h + 3) * 32 + t], a3);
    }
    reconT[t * BB + b] = (a0 + a1) + (a2 + a3);
  }
}

// ---------------------------------------------------------------------------
// Main: 512 blocks x 512 thr. block = (d = bx>>2, bh = bx&3 -> 64 b rows).
// 8 waves: phase1 split (rt = w>>1, 2 m-tiles); phase2: wave owns 4 k,
// lc1T slice held in registers, loops 4 row-tiles.
// ---------------------------------------------------------------------------
__global__ __launch_bounds__(512, 4) void main_kernel(
    const float* __restrict__ lc2w, const float* __restrict__ betab,
    const char* __restrict__ ws, float* __restrict__ out)
{
  const int bx = blockIdx.x;
  const int d = bx >> 2;
  const int bh = bx & 3;
  const int tid = threadIdx.x;
  const int wave = tid >> 6, lane = tid & 63;
  const int g = lane >> 4, l15 = lane & 15;

  const short* __restrict__ xbf   = (const short*)(ws + 65536);
  const short* __restrict__ lc1T  = (const short*)(ws + 131072);
  const float* __restrict__ lc1bs = (const float*)(ws + 262144);
  const float* __restrict__ lc2bq = (const float*)(ws + 266240);
  const float* __restrict__ b1s   = (const float*)(ws + 270336) + d * MM1;
  const short* __restrict__ w1bf  = (const short*)(ws + 303104) + d * (MM1 * DD);
  const float* __restrict__ betaT = (const float*)(ws + 32768);
  const float* __restrict__ recT  = (const float*)(ws + 0);

  __shared__ __align__(16) short sS[64 * 64];      // sigma(phi), swizzled, 8KB
  __shared__ __align__(16) float cS[1024];         // -lc1b*LOG2E
  __shared__ __align__(16) float wS[1024];         // lc2w
  __shared__ float lbq[32];
  __shared__ float yred[8][64][2];

  // stage bias/weight tables
  if (tid < 256)      ((f32x4*)cS)[tid]       = ((const f32x4*)lc1bs)[tid];
  else if (tid < 512) ((f32x4*)wS)[tid - 256] = ((const f32x4*)lc2w)[tid - 256];
  if (tid < 32) lbq[tid] = lc2bq[tid];

  // phase-2 A fragments: this wave's 4 k-slices of lc1T, in registers for good
  bf16x8 Af[4][2][2];
  #pragma unroll
  for (int kk = 0; kk < 4; ++kk)
    #pragma unroll
    for (int nh = 0; nh < 2; ++nh)
      #pragma unroll
      for (int mh = 0; mh < 2; ++mh)
        Af[kk][nh][mh] = *(const bf16x8*)(
            lc1T + ((wave * 4 + kk) * 32 + nh * 16 + l15) * 64 + mh * 32 + g * 8);

  // ---------------- phase 1: sigma(phi) for this block's 64 b rows ---------
  {
    const int rt1 = wave >> 1, mt0 = (wave & 1) * 2;
    bf16x8 xa[4];
    #pragma unroll
    for (int ks = 0; ks < 4; ++ks)
      xa[ks] = *(const bf16x8*)(
          xbf + (bh * 64 + rt1 * 16 + l15) * DD + ks * 32 + g * 8);
    #pragma unroll
    for (int mi = 0; mi < 2; ++mi) {
      const int m = (mt0 + mi) * 16 + l15;
      f32x4 acc = {0.f, 0.f, 0.f, 0.f};
      #pragma unroll
      for (int ks = 0; ks < 4; ++ks) {
        bf16x8 wb = *(const bf16x8*)(w1bf + m * DD + ks * 32 + g * 8);
        acc = __builtin_amdgcn_mfma_f32_16x16x32_bf16(xa[ks], wb, acc, 0, 0, 0);
      }
      const float cpre = b1s[m];
      #pragma unroll
      for (int r = 0; r < 4; ++r) {
        const int bl = rt1 * 16 + g * 4 + r;
        sS[bl * 64 + ((m & ~7) ^ ((bl & 7) << 3)) + (m & 7)] =
            f2b(sigm_pre(acc[r], cpre));
      }
    }
  }
  __syncthreads();

  // ---------------- phase 2: 4 row-tiles, wave-owned 4 k -------------------
  float y1p[4] = {0, 0, 0, 0}, y2p[4] = {0, 0, 0, 0};
  #pragma unroll
  for (int rt = 0; rt < 4; ++rt) {
    const int b = rt * 16 + l15;
    const int bsw = (b & 7) << 3;
    const bf16x8 sa0 = *(const bf16x8*)&sS[b * 64 + ((g * 8) ^ bsw)];
    const bf16x8 sa1 = *(const bf16x8*)&sS[b * 64 + ((32 + g * 8) ^ bsw)];
    f32x4 acc[4][2];
    #pragma unroll
    for (int kk = 0; kk < 4; ++kk)
      #pragma unroll
      for (int nh = 0; nh < 2; ++nh) {
        f32x4 a = {0.f, 0.f, 0.f, 0.f};
        a = __builtin_amdgcn_mfma_f32_16x16x32_bf16(Af[kk][nh][0], sa0, a, 0, 0, 0);
        a = __builtin_amdgcn_mfma_f32_16x16x32_bf16(Af[kk][nh][1], sa1, a, 0, 0, 0);
        acc[kk][nh] = a;
      }
    const int gb = bh * 64 + b;
    #pragma unroll
    for (int kk = 0; kk < 4; ++kk) {
      const int k = wave * 4 + kk;
      float v = lbq[k];
      #pragma unroll
      for (int nh = 0; nh < 2; ++nh) {
        const f32x4 c4 = *(const f32x4*)&cS[k * 32 + nh * 16 + g * 4];
        const f32x4 w4 = *(const f32x4*)&wS[k * 32 + nh * 16 + g * 4];
        #pragma unroll
        for (int r = 0; r < 4; ++r)
          v = fmaf(sigm_pre(acc[kk][nh][r], c4[r]), w4[r], v);
      }
      y1p[rt] = fmaf(v, betaT[k * BB + gb], y1p[rt]);
      y2p[rt] = fmaf(v, recT[k * BB + gb], y2p[rt]);
    }
  }

  // ---------------- reduce: g-groups (shfl), waves (LDS) -------------------
  #pragma unroll
  for (int rt = 0; rt < 4; ++rt) {
    y1p[rt] += __shfl_xor(y1p[rt], 16, 64);
    y1p[rt] += __shfl_xor(y1p[rt], 32, 64);
    y2p[rt] += __shfl_xor(y2p[rt], 16, 64);
    y2p[rt] += __shfl_xor(y2p[rt], 32, 64);
  }
  if (g == 0) {
    #pragma unroll
    for (int rt = 0; rt < 4; ++rt) {
      yred[wave][rt * 16 + l15][0] = y1p[rt];
      yred[wave][rt * 16 + l15][1] = y2p[rt];
    }
  }
  __syncthreads();
  if (tid < 128) {
    const int bl = tid >> 1, o = tid & 1;
    float s = 0.f;
    #pragma unroll
    for (int w = 0; w < 8; ++w) s += yred[w][bl][o];
    const int b = bh * 64 + bl;
    out[o * (BB * DD) + b * DD + d] = s + betab[b];
  }
}

// ---------------------------------------------------------------------------
extern "C" void kernel_launch(void* const* d_in, const int* in_sizes, int n_in,
                              void* d_out, int out_size, void* d_ws, size_t ws_size,
                              hipStream_t stream) {
  const float* x     = (const float*)d_in[0];
  const float* W1p   = (const float*)d_in[1];
  const float* W1n   = (const float*)d_in[2];
  const float* b1p   = (const float*)d_in[3];
  const float* b1n   = (const float*)d_in[4];
  const float* lc1w  = (const float*)d_in[5];
  const float* lc1b  = (const float*)d_in[6];
  const float* lc2w  = (const float*)d_in[7];
  const float* lc2b  = (const float*)d_in[8];
  const float* betaw = (const float*)d_in[9];
  const float* betab = (const float*)d_in[10];
  const float* enc1w = (const float*)d_in[11];
  const float* enc1b = (const float*)d_in[12];
  const float* enc2w = (const float*)d_in[13];
  const float* enc2b = (const float*)d_in[14];
  const float* muw   = (const float*)d_in[15];
  const float* mub   = (const float*)d_in[16];
  const float* lvw   = (const float*)d_in[17];
  const float* lvb   = (const float*)d_in[18];
  const float* dec1w = (const float*)d_in[19];
  const float* dec1b = (const float*)d_in[20];
  const float* dec2w = (const float*)d_in[21];
  const float* dec2b = (const float*)d_in[22];
  const float* dec3w = (const float*)d_in[23];
  const float* dec3b = (const float*)d_in[24];
  const float* eps   = (const float*)d_in[25];

  float* out    = (float*)d_out;
  char*  ws     = (char*)d_ws;
  float* mu_out = out + BB * DD * 2;            // 65536
  float* lv_out = mu_out + BB * 32;             // 73728

  combo_kernel<<<dim3(1280), dim3(256), 0, stream>>>(
      x, W1p, W1n, b1p, b1n, lc1w, lc1b, lc2b, betaw,
      enc1w, enc1b, enc2w, enc2b, muw, mub, lvw, lvb,
      dec1w, dec1b, dec2w, dec2b, dec3w, dec3b, eps,
      ws, mu_out, lv_out);

  main_kernel<<<dim3(512), dim3(512), 0, stream>>>(
      lc2w, betab, (const char*)ws, out);
}

// Round 4
// 135.627 us; speedup vs baseline: 1.1086x; 1.1086x over previous
//
#include <hip/hip_runtime.h>
#include <stdint.h>

#define BB 256
#define DD 128
#define KK 32
#define MM1 64
#define MM2 32

typedef __attribute__((ext_vector_type(8))) short bf16x8;
typedef __attribute__((ext_vector_type(4))) float f32x4;

#define LOG2E 1.44269504088896f

// ---- ws layout (bytes) ----
// 0       reconT  f32 [32][256]   (vae)        32KB
// 32768   betaT   f32 [32][256]   (prep)       32KB
// 65536   xbf     bf16[256][128]  (prep)       64KB
// 131072  lc1T    bf16[1024][64]  (prep) rows cp=k*32+n, cols m   128KB
// 262144  lc1bs   f32 [32][32]  = -lc1b*LOG2E  4KB
// 266240  lc2bq   f32 [32]      = 0.25*lc2b
// 270336  b1s     f32 [128][64] = -(b1p-b1n)*LOG2E   32KB
// 303104  w1bf    bf16[128][64][128]           2MB

__device__ __forceinline__ short f2b(float f) {
  uint32_t u = __builtin_bit_cast(uint32_t, f);
  u += 0x7FFFu + ((u >> 16) & 1u);          // RNE to bf16
  return (short)(u >> 16);
}
__device__ __forceinline__ float sigm_pre(float acc, float cpre) {
  // sigmoid(acc + bias) with cpre = -bias*LOG2E
  return __builtin_amdgcn_rcpf(
      1.0f + __builtin_amdgcn_exp2f(fmaf(acc, -LOG2E, cpre)));
}

// ---------------------------------------------------------------------------
// Combo kernel: blocks 0..1023 = prep (dtype conversion / transposes),
//               blocks 1024..1279 = VAE (one block per sample b).
// ---------------------------------------------------------------------------
__global__ __launch_bounds__(256) void combo_kernel(
    const float* __restrict__ x, const float* __restrict__ W1p,
    const float* __restrict__ W1n, const float* __restrict__ b1p,
    const float* __restrict__ b1n, const float* __restrict__ lc1w,
    const float* __restrict__ lc1b, const float* __restrict__ lc2b,
    const float* __restrict__ betaw,
    const float* __restrict__ enc1w, const float* __restrict__ enc1b,
    const float* __restrict__ enc2w, const float* __restrict__ enc2b,
    const float* __restrict__ muw,  const float* __restrict__ mub,
    const float* __restrict__ lvw,  const float* __restrict__ lvb,
    const float* __restrict__ dec1w, const float* __restrict__ dec1b,
    const float* __restrict__ dec2w, const float* __restrict__ dec2b,
    const float* __restrict__ dec3w, const float* __restrict__ dec3b,
    const float* __restrict__ eps,
    char* __restrict__ ws, float* __restrict__ mu_out,
    float* __restrict__ lv_out)
{
  const int bx = blockIdx.x;
  if (bx < 1024) {
    // ---------------- prep ----------------
    const int tid = bx * 256 + threadIdx.x;   // 0..262143
    { // W1bf = bf16(W1p - W1n), linear [d][m][i], 262144 float4
      float4 a = ((const float4*)W1p)[tid];
      float4 b = ((const float4*)W1n)[tid];
      short4 s;
      s.x = f2b(a.x - b.x); s.y = f2b(a.y - b.y);
      s.z = f2b(a.z - b.z); s.w = f2b(a.w - b.w);
      ((short4*)(ws + 303104))[tid] = s;
    }
    if (tid < 8192) { // xbf
      float4 v = ((const float4*)x)[tid];
      short4 s;
      s.x = f2b(v.x); s.y = f2b(v.y); s.z = f2b(v.z); s.w = f2b(v.w);
      ((short4*)(ws + 65536))[tid] = s;
    }
    if (tid < 65536) { // lc1T[(k*32+n)*64 + m] = lc1w[k][m][n]
      int k = tid >> 11, n = (tid >> 6) & 31, m = tid & 63;
      ((short*)(ws + 131072))[tid] = f2b(lc1w[k * 2048 + m * 32 + n]);
    }
    if (tid < 8192) { // betaT[k*256 + b]
      ((float*)(ws + 32768))[tid] = betaw[(tid & 255) * 32 + (tid >> 8)];
    }
    if (tid < 1024) { ((float*)(ws + 262144))[tid] = -lc1b[tid] * LOG2E; }
    if (tid < 32) { ((float*)(ws + 266240))[tid] = 0.25f * lc2b[tid]; }
    if (tid < 8192) { // b1s
      ((float*)(ws + 270336))[tid] = -(b1p[tid] - b1n[tid]) * LOG2E;
    }
    return;
  }

  // ---------------- VAE (one block per sample) ----------------
  const int b = bx - 1024, t = threadIdx.x;
  float* reconT = (float*)ws;
  __shared__ float bw[KK], e1[128], e2[64], zz[32], d1s[64], d2s[128];
  if (t < KK) bw[t] = betaw[b * KK + t];
  __syncthreads();
  if (t < 128) { // enc1: K->128
    float a0 = enc1b[t], a1 = 0.f;
    #pragma unroll
    for (int k = 0; k < KK; k += 2) {
      a0 = fmaf(bw[k], enc1w[k * 128 + t], a0);
      a1 = fmaf(bw[k + 1], enc1w[(k + 1) * 128 + t], a1);
    }
    e1[t] = fmaxf(a0 + a1, 0.f);
  }
  __syncthreads();
  if (t < 64) { // enc2: 128->64
    float a0 = enc2b[t], a1 = 0.f, a2 = 0.f, a3 = 0.f;
    #pragma unroll 8
    for (int h = 0; h < 128; h += 4) {
      a0 = fmaf(e1[h], enc2w[h * 64 + t], a0);
      a1 = fmaf(e1[h + 1], enc2w[(h + 1) * 64 + t], a1);
      a2 = fmaf(e1[h + 2], enc2w[(h + 2) * 64 + t], a2);
      a3 = fmaf(e1[h + 3], enc2w[(h + 3) * 64 + t], a3);
    }
    e2[t] = fmaxf((a0 + a1) + (a2 + a3), 0.f);
  }
  __syncthreads();
  if (t < 32) { // mu / logvar / z
    float m0 = mub[t], m1 = 0.f, l0 = lvb[t], l1 = 0.f;
    #pragma unroll 8
    for (int h = 0; h < 64; h += 2) {
      float ea = e2[h], eb = e2[h + 1];
      m0 = fmaf(ea, muw[h * 32 + t], m0);
      m1 = fmaf(eb, muw[(h + 1) * 32 + t], m1);
      l0 = fmaf(ea, lvw[h * 32 + t], l0);
      l1 = fmaf(eb, lvw[(h + 1) * 32 + t], l1);
    }
    float m = m0 + m1, l = l0 + l1;
    mu_out[b * 32 + t] = m;
    lv_out[b * 32 + t] = l;
    zz[t] = fmaf(eps[b * 32 + t], __expf(0.5f * l), m);
  }
  __syncthreads();
  if (t < 64) { // dec1: 32->64
    float a0 = dec1b[t], a1 = 0.f;
    #pragma unroll
    for (int l = 0; l < 32; l += 2) {
      a0 = fmaf(zz[l], dec1w[l * 64 + t], a0);
      a1 = fmaf(zz[l + 1], dec1w[(l + 1) * 64 + t], a1);
    }
    d1s[t] = fmaxf(a0 + a1, 0.f);
  }
  __syncthreads();
  if (t < 128) { // dec2: 64->128
    float a0 = dec2b[t], a1 = 0.f, a2 = 0.f, a3 = 0.f;
    #pragma unroll 8
    for (int h = 0; h < 64; h += 4) {
      a0 = fmaf(d1s[h], dec2w[h * 128 + t], a0);
      a1 = fmaf(d1s[h + 1], dec2w[(h + 1) * 128 + t], a1);
      a2 = fmaf(d1s[h + 2], dec2w[(h + 2) * 128 + t], a2);
      a3 = fmaf(d1s[h + 3], dec2w[(h + 3) * 128 + t], a3);
    }
    d2s[t] = fmaxf((a0 + a1) + (a2 + a3), 0.f);
  }
  __syncthreads();
  if (t < 32) { // dec3: 128->K, transposed write
    float a0 = dec3b[t], a1 = 0.f, a2 = 0.f, a3 = 0.f;
    #pragma unroll 8
    for (int h = 0; h < 128; h += 4) {
      a0 = fmaf(d2s[h], dec3w[h * 32 + t], a0);
      a1 = fmaf(d2s[h + 1], dec3w[(h + 1) * 32 + t], a1);
      a2 = fmaf(d2s[h + 2], dec3w[(h + 2) * 32 + t], a2);
      a3 = fmaf(d2s[h + 3], dec3w[(h + 3) * 32 + t], a3);
    }
    reconT[t * BB + b] = (a0 + a1) + (a2 + a3);
  }
}

// ---------------------------------------------------------------------------
// Main: 256 blocks x 1024 thr. block = (d2 = bx>>2 -> 2 d's, bq = bx&3 -> 64 b).
// 16 waves = (dsel:2) x (ksel:8, 4 k each). Phase 2 is k-outer (A-frags 16
// VGPRs, reused over 4 row-tiles) -> no spill, lc1T L2 traffic halved.
// ---------------------------------------------------------------------------
__global__ __launch_bounds__(1024) void main_kernel(
    const float* __restrict__ lc2w, const float* __restrict__ betab,
    const char* __restrict__ ws, float* __restrict__ out)
{
  const int bx = blockIdx.x;
  const int d2 = bx >> 2;
  const int bq = bx & 3;
  const int tid = threadIdx.x;
  const int wv = tid >> 6, lane = tid & 63;
  const int g = lane >> 4, l15 = lane & 15;

  const short* __restrict__ xbf   = (const short*)(ws + 65536);
  const short* __restrict__ lc1T  = (const short*)(ws + 131072);
  const float* __restrict__ lc1bs = (const float*)(ws + 262144);
  const float* __restrict__ lc2bq = (const float*)(ws + 266240);
  const float* __restrict__ b1s   = (const float*)(ws + 270336);
  const short* __restrict__ w1bf  = (const short*)(ws + 303104);
  const float* __restrict__ betaT = (const float*)(ws + 32768);
  const float* __restrict__ recT  = (const float*)(ws + 0);

  __shared__ __align__(16) short sS[2][64 * 64];   // sigma(phi) per d, 16KB
  __shared__ float yred[16][64][2];                // 8KB

  const int dsel = wv >> 3;
  const int d = d2 * 2 + dsel;

  // ---------------- phase 1: sigma(phi) for (d, 64 b x 64 m) ---------------
  {
    const int sub = wv & 7;
    const int bt = sub >> 1, mtp = (sub & 1) * 2;
    const short* xrow = xbf + (bq * 64 + bt * 16 + l15) * DD + g * 8;
    bf16x8 xa[4];
    #pragma unroll
    for (int ks = 0; ks < 4; ++ks)
      xa[ks] = *(const bf16x8*)(xrow + ks * 32);
    const short* wrow = w1bf + d * (MM1 * DD);
    #pragma unroll
    for (int mi = 0; mi < 2; ++mi) {
      const int m = (mtp + mi) * 16 + l15;
      f32x4 acc = {0.f, 0.f, 0.f, 0.f};
      #pragma unroll
      for (int ks = 0; ks < 4; ++ks) {
        bf16x8 wb = *(const bf16x8*)(wrow + m * DD + ks * 32 + g * 8);
        acc = __builtin_amdgcn_mfma_f32_16x16x32_bf16(xa[ks], wb, acc, 0, 0, 0);
      }
      const float cpre = b1s[d * MM1 + m];
      #pragma unroll
      for (int r = 0; r < 4; ++r) {
        const int bl = bt * 16 + g * 4 + r;
        sS[dsel][bl * 64 + ((m & ~7) ^ ((bl & 7) << 3)) + (m & 7)] =
            f2b(sigm_pre(acc[r], cpre));
      }
    }
  }
  __syncthreads();

  // ---------------- phase 2: k-outer, 4 row-tiles inner --------------------
  const int ksel = wv & 7;
  float y1p[4] = {0, 0, 0, 0}, y2p[4] = {0, 0, 0, 0};
  const short* sbase = sS[dsel];

  #pragma unroll
  for (int kk = 0; kk < 4; ++kk) {
    const int k = ksel * 4 + kk;
    // A-fragments (loop-invariant over rt): rows cp = k*32 + nh*16 + l15
    const short* ap = lc1T + (k * 32 + l15) * 64 + g * 8;
    const bf16x8 A00 = *(const bf16x8*)(ap);
    const bf16x8 A01 = *(const bf16x8*)(ap + 32);
    const bf16x8 A10 = *(const bf16x8*)(ap + 16 * 64);
    const bf16x8 A11 = *(const bf16x8*)(ap + 16 * 64 + 32);
    const f32x4 c40 = *(const f32x4*)(lc1bs + k * 32 + g * 4);
    const f32x4 c41 = *(const f32x4*)(lc1bs + k * 32 + 16 + g * 4);
    const f32x4 w40 = *(const f32x4*)(lc2w + k * 32 + g * 4);
    const f32x4 w41 = *(const f32x4*)(lc2w + k * 32 + 16 + g * 4);
    const float lb = lc2bq[k];
    const float* bTk = betaT + k * BB + bq * 64 + l15;
    const float* rTk = recT + k * BB + bq * 64 + l15;

    #pragma unroll
    for (int rt = 0; rt < 4; ++rt) {
      const int b = rt * 16 + l15;
      const int bsw = (b & 7) << 3;
      const bf16x8 sa0 = *(const bf16x8*)&sbase[b * 64 + ((g * 8) ^ bsw)];
      const bf16x8 sa1 = *(const bf16x8*)&sbase[b * 64 + ((32 + g * 8) ^ bsw)];
      f32x4 a0 = {0.f, 0.f, 0.f, 0.f}, a1 = {0.f, 0.f, 0.f, 0.f};
      a0 = __builtin_amdgcn_mfma_f32_16x16x32_bf16(A00, sa0, a0, 0, 0, 0);
      a0 = __builtin_amdgcn_mfma_f32_16x16x32_bf16(A01, sa1, a0, 0, 0, 0);
      a1 = __builtin_amdgcn_mfma_f32_16x16x32_bf16(A10, sa0, a1, 0, 0, 0);
      a1 = __builtin_amdgcn_mfma_f32_16x16x32_bf16(A11, sa1, a1, 0, 0, 0);
      float v = lb;
      #pragma unroll
      for (int r = 0; r < 4; ++r) {
        v = fmaf(sigm_pre(a0[r], c40[r]), w40[r], v);
        v = fmaf(sigm_pre(a1[r], c41[r]), w41[r], v);
      }
      y1p[rt] = fmaf(v, bTk[rt * 16], y1p[rt]);
      y2p[rt] = fmaf(v, rTk[rt * 16], y2p[rt]);
    }
  }

  // ---------------- reduce: g-groups (shfl), waves (LDS) -------------------
  #pragma unroll
  for (int rt = 0; rt < 4; ++rt) {
    y1p[rt] += __shfl_xor(y1p[rt], 16, 64);
    y1p[rt] += __shfl_xor(y1p[rt], 32, 64);
    y2p[rt] += __shfl_xor(y2p[rt], 16, 64);
    y2p[rt] += __shfl_xor(y2p[rt], 32, 64);
  }
  if (g == 0) {
    #pragma unroll
    for (int rt = 0; rt < 4; ++rt) {
      yred[wv][rt * 16 + l15][0] = y1p[rt];
      yred[wv][rt * 16 + l15][1] = y2p[rt];
    }
  }
  __syncthreads();
  if (tid < 256) {
    const int o = tid & 1, bl = (tid >> 1) & 63, ds = tid >> 7;
    float s = 0.f;
    #pragma unroll
    for (int j = 0; j < 8; ++j) s += yred[ds * 8 + j][bl][o];
    const int gb = bq * 64 + bl;
    out[o * (BB * DD) + gb * DD + d2 * 2 + ds] = s + betab[gb];
  }
}

// ---------------------------------------------------------------------------
extern "C" void kernel_launch(void* const* d_in, const int* in_sizes, int n_in,
                              void* d_out, int out_size, void* d_ws, size_t ws_size,
                              hipStream_t stream) {
  const float* x     = (const float*)d_in[0];
  const float* W1p   = (const float*)d_in[1];
  const float* W1n   = (const float*)d_in[2];
  const float* b1p   = (const float*)d_in[3];
  const float* b1n   = (const float*)d_in[4];
  const float* lc1w  = (const float*)d_in[5];
  const float* lc1b  = (const float*)d_in[6];
  const float* lc2w  = (const float*)d_in[7];
  const float* lc2b  = (const float*)d_in[8];
  const float* betaw = (const float*)d_in[9];
  const float* betab = (const float*)d_in[10];
  const float* enc1w = (const float*)d_in[11];
  const float* enc1b = (const float*)d_in[12];
  const float* enc2w = (const float*)d_in[13];
  const float* enc2b = (const float*)d_in[14];
  const float* muw   = (const float*)d_in[15];
  const float* mub   = (const float*)d_in[16];
  const float* lvw   = (const float*)d_in[17];
  const float* lvb   = (const float*)d_in[18];
  const float* dec1w = (const float*)d_in[19];
  const float* dec1b = (const float*)d_in[20];
  const float* dec2w = (const float*)d_in[21];
  const float* dec2b = (const float*)d_in[22];
  const float* dec3w = (const float*)d_in[23];
  const float* dec3b = (const float*)d_in[24];
  const float* eps   = (const float*)d_in[25];

  float* out    = (float*)d_out;
  char*  ws     = (char*)d_ws;
  float* mu_out = out + BB * DD * 2;            // 65536
  float* lv_out = mu_out + BB * 32;             // 73728

  combo_kernel<<<dim3(1280), dim3(256), 0, stream>>>(
      x, W1p, W1n, b1p, b1n, lc1w, lc1b, lc2b, betaw,
      enc1w, enc1b, enc2w, enc2b, muw, mub, lvw, lvb,
      dec1w, dec1b, dec2w, dec2b, dec3w, dec3b, eps,
      ws, mu_out, lv_out);

  main_kernel<<<dim3(256), dim3(1024), 0, stream>>>(
      lc2w, betab, (const char*)ws, out);
}

// Round 5
// 135.351 us; speedup vs baseline: 1.1108x; 1.0020x over previous
//
#include <hip/hip_runtime.h>
#include <stdint.h>

#define BB 256
#define DD 128
#define KK 32
#define MM1 64
#define MM2 32

typedef __attribute__((ext_vector_type(8))) short bf16x8;
typedef __attribute__((ext_vector_type(4))) float f32x4;

#define LOG2E 1.44269504088896f

// ---- ws layout (bytes) ----
// 0       reconT  f32 [32][256]   (vae)        32KB
// 32768   betaT   f32 [32][256]   (prep)       32KB
// 65536   xbf     bf16[256][128]  (prep)       64KB
// 131072  lc1T    bf16[1024][64]  (prep) rows cp=k*32+n, cols m   128KB
// 262144  lc1bs   f32 [32][32]  = -lc1b*LOG2E  4KB
// 266240  lc2bq   f32 [32]      = 0.25*lc2b
// 270336  b1s     f32 [128][64] = -(b1p-b1n)*LOG2E   32KB
// 303104  w1bf    bf16[128][64][128]           2MB

__device__ __forceinline__ short f2b(float f) {
  uint32_t u = __builtin_bit_cast(uint32_t, f);
  u += 0x7FFFu + ((u >> 16) & 1u);          // RNE to bf16
  return (short)(u >> 16);
}
__device__ __forceinline__ float sigm_pre(float acc, float cpre) {
  // sigmoid(acc + bias) with cpre = -bias*LOG2E
  return __builtin_amdgcn_rcpf(
      1.0f + __builtin_amdgcn_exp2f(fmaf(acc, -LOG2E, cpre)));
}

// ---------------------------------------------------------------------------
// Combo kernel: blocks 0..1023 = prep (dtype conversion / transposes),
//               blocks 1024..1279 = VAE (one block per sample b).
// ---------------------------------------------------------------------------
__global__ __launch_bounds__(256) void combo_kernel(
    const float* __restrict__ x, const float* __restrict__ W1p,
    const float* __restrict__ W1n, const float* __restrict__ b1p,
    const float* __restrict__ b1n, const float* __restrict__ lc1w,
    const float* __restrict__ lc1b, const float* __restrict__ lc2b,
    const float* __restrict__ betaw,
    const float* __restrict__ enc1w, const float* __restrict__ enc1b,
    const float* __restrict__ enc2w, const float* __restrict__ enc2b,
    const float* __restrict__ muw,  const float* __restrict__ mub,
    const float* __restrict__ lvw,  const float* __restrict__ lvb,
    const float* __restrict__ dec1w, const float* __restrict__ dec1b,
    const float* __restrict__ dec2w, const float* __restrict__ dec2b,
    const float* __restrict__ dec3w, const float* __restrict__ dec3b,
    const float* __restrict__ eps,
    char* __restrict__ ws, float* __restrict__ mu_out,
    float* __restrict__ lv_out)
{
  const int bx = blockIdx.x;
  if (bx < 1024) {
    // ---------------- prep ----------------
    const int tid = bx * 256 + threadIdx.x;   // 0..262143
    { // W1bf = bf16(W1p - W1n), linear [d][m][i], 262144 float4
      float4 a = ((const float4*)W1p)[tid];
      float4 b = ((const float4*)W1n)[tid];
      short4 s;
      s.x = f2b(a.x - b.x); s.y = f2b(a.y - b.y);
      s.z = f2b(a.z - b.z); s.w = f2b(a.w - b.w);
      ((short4*)(ws + 303104))[tid] = s;
    }
    if (tid < 8192) { // xbf
      float4 v = ((const float4*)x)[tid];
      short4 s;
      s.x = f2b(v.x); s.y = f2b(v.y); s.z = f2b(v.z); s.w = f2b(v.w);
      ((short4*)(ws + 65536))[tid] = s;
    }
    if (tid < 65536) { // lc1T[(k*32+n)*64 + m] = lc1w[k][m][n]
      int k = tid >> 11, n = (tid >> 6) & 31, m = tid & 63;
      ((short*)(ws + 131072))[tid] = f2b(lc1w[k * 2048 + m * 32 + n]);
    }
    if (tid < 8192) { // betaT[k*256 + b]
      ((float*)(ws + 32768))[tid] = betaw[(tid & 255) * 32 + (tid >> 8)];
    }
    if (tid < 1024) { ((float*)(ws + 262144))[tid] = -lc1b[tid] * LOG2E; }
    if (tid < 32) { ((float*)(ws + 266240))[tid] = 0.25f * lc2b[tid]; }
    if (tid < 8192) { // b1s
      ((float*)(ws + 270336))[tid] = -(b1p[tid] - b1n[tid]) * LOG2E;
    }
    return;
  }

  // ---------------- VAE (one block per sample) ----------------
  const int b = bx - 1024, t = threadIdx.x;
  float* reconT = (float*)ws;
  __shared__ float bw[KK], e1[128], e2[64], zz[32], d1s[64], d2s[128];
  if (t < KK) bw[t] = betaw[b * KK + t];
  __syncthreads();
  if (t < 128) { // enc1: K->128
    float a0 = enc1b[t], a1 = 0.f;
    #pragma unroll
    for (int k = 0; k < KK; k += 2) {
      a0 = fmaf(bw[k], enc1w[k * 128 + t], a0);
      a1 = fmaf(bw[k + 1], enc1w[(k + 1) * 128 + t], a1);
    }
    e1[t] = fmaxf(a0 + a1, 0.f);
  }
  __syncthreads();
  if (t < 64) { // enc2: 128->64
    float a0 = enc2b[t], a1 = 0.f, a2 = 0.f, a3 = 0.f;
    #pragma unroll 8
    for (int h = 0; h < 128; h += 4) {
      a0 = fmaf(e1[h], enc2w[h * 64 + t], a0);
      a1 = fmaf(e1[h + 1], enc2w[(h + 1) * 64 + t], a1);
      a2 = fmaf(e1[h + 2], enc2w[(h + 2) * 64 + t], a2);
      a3 = fmaf(e1[h + 3], enc2w[(h + 3) * 64 + t], a3);
    }
    e2[t] = fmaxf((a0 + a1) + (a2 + a3), 0.f);
  }
  __syncthreads();
  if (t < 32) { // mu / logvar / z
    float m0 = mub[t], m1 = 0.f, l0 = lvb[t], l1 = 0.f;
    #pragma unroll 8
    for (int h = 0; h < 64; h += 2) {
      float ea = e2[h], eb = e2[h + 1];
      m0 = fmaf(ea, muw[h * 32 + t], m0);
      m1 = fmaf(eb, muw[(h + 1) * 32 + t], m1);
      l0 = fmaf(ea, lvw[h * 32 + t], l0);
      l1 = fmaf(eb, lvw[(h + 1) * 32 + t], l1);
    }
    float m = m0 + m1, l = l0 + l1;
    mu_out[b * 32 + t] = m;
    lv_out[b * 32 + t] = l;
    zz[t] = fmaf(eps[b * 32 + t], __expf(0.5f * l), m);
  }
  __syncthreads();
  if (t < 64) { // dec1: 32->64
    float a0 = dec1b[t], a1 = 0.f;
    #pragma unroll
    for (int l = 0; l < 32; l += 2) {
      a0 = fmaf(zz[l], dec1w[l * 64 + t], a0);
      a1 = fmaf(zz[l + 1], dec1w[(l + 1) * 64 + t], a1);
    }
    d1s[t] = fmaxf(a0 + a1, 0.f);
  }
  __syncthreads();
  if (t < 128) { // dec2: 64->128
    float a0 = dec2b[t], a1 = 0.f, a2 = 0.f, a3 = 0.f;
    #pragma unroll 8
    for (int h = 0; h < 64; h += 4) {
      a0 = fmaf(d1s[h], dec2w[h * 128 + t], a0);
      a1 = fmaf(d1s[h + 1], dec2w[(h + 1) * 128 + t], a1);
      a2 = fmaf(d1s[h + 2], dec2w[(h + 2) * 128 + t], a2);
      a3 = fmaf(d1s[h + 3], dec2w[(h + 3) * 128 + t], a3);
    }
    d2s[t] = fmaxf((a0 + a1) + (a2 + a3), 0.f);
  }
  __syncthreads();
  if (t < 32) { // dec3: 128->K, transposed write
    float a0 = dec3b[t], a1 = 0.f, a2 = 0.f, a3 = 0.f;
    #pragma unroll 8
    for (int h = 0; h < 128; h += 4) {
      a0 = fmaf(d2s[h], dec3w[h * 32 + t], a0);
      a1 = fmaf(d2s[h + 1], dec3w[(h + 1) * 32 + t], a1);
      a2 = fmaf(d2s[h + 2], dec3w[(h + 2) * 32 + t], a2);
      a3 = fmaf(d2s[h + 3], dec3w[(h + 3) * 32 + t], a3);
    }
    reconT[t * BB + b] = (a0 + a1) + (a2 + a3);
  }
}

// ---------------------------------------------------------------------------
// Main: 512 blocks x 512 thr. block = (d = bx>>2, bq = bx&3 -> 64 b rows).
// 8 waves. Phase 1: wave -> (bt = wv>>1, 2 m-tiles). Phase 2: wave owns 4 k,
// k-outer (A-frags 16 VGPRs live), 4 row-tiles inner; ALL epilogue operands
// (betaT/reconT/lc1bs/lc2w/lc2b slices) staged in LDS -> 16 VMEM/thread.
// ~36KB LDS, no min-wave bound -> 2 blocks/CU for phase overlap.
// ---------------------------------------------------------------------------
__global__ __launch_bounds__(512) void main_kernel(
    const float* __restrict__ lc2w, const float* __restrict__ betab,
    const char* __restrict__ ws, float* __restrict__ out)
{
  const int bx = blockIdx.x;
  const int d = bx >> 2;
  const int bq = bx & 3;
  const int tid = threadIdx.x;
  const int wv = tid >> 6, lane = tid & 63;
  const int g = lane >> 4, l15 = lane & 15;

  const short* __restrict__ xbf   = (const short*)(ws + 65536);
  const short* __restrict__ lc1T  = (const short*)(ws + 131072);
  const float* __restrict__ lc1bs = (const float*)(ws + 262144);
  const float* __restrict__ lc2bq = (const float*)(ws + 266240);
  const float* __restrict__ b1s   = (const float*)(ws + 270336);
  const short* __restrict__ w1bf  = (const short*)(ws + 303104);
  const float* __restrict__ betaT = (const float*)(ws + 32768);
  const float* __restrict__ recT  = (const float*)(ws + 0);

  __shared__ __align__(16) short sS[64 * 64];      // sigma(phi), swizzled, 8KB
  __shared__ __align__(16) float betaS[KK * 64];   // 8KB  [k][b-local]
  __shared__ __align__(16) float reconS[KK * 64];  // 8KB
  __shared__ __align__(16) float cS[KK * MM2];     // 4KB  -lc1b*LOG2E
  __shared__ __align__(16) float wSS[KK * MM2];    // 4KB  lc2w
  __shared__ float lbq[KK];
  __shared__ float yred[8][64][2];                 // 4KB

  // ---------------- stage epilogue operands into LDS -----------------------
  { // betaS/reconS: [32 k][64 b], source rows are 256-wide
    const int k = tid >> 4, j = (tid & 15) * 4;
    *(float4*)&betaS[k * 64 + j]  = *(const float4*)&betaT[k * BB + bq * 64 + j];
    *(float4*)&reconS[k * 64 + j] = *(const float4*)&recT[k * BB + bq * 64 + j];
  }
  if (tid < 256)      ((f32x4*)cS)[tid]        = ((const f32x4*)lc1bs)[tid];
  else if (tid < 512) ((f32x4*)wSS)[tid - 256] = ((const f32x4*)lc2w)[tid - 256];
  if (tid < KK) lbq[tid] = lc2bq[tid];

  // ---------------- phase 1: sigma(phi) for (d, 64 b x 64 m) ---------------
  {
    const int bt = wv >> 1, mtp = (wv & 1) * 2;
    const short* xrow = xbf + (bq * 64 + bt * 16 + l15) * DD + g * 8;
    bf16x8 xa[4];
    #pragma unroll
    for (int ks = 0; ks < 4; ++ks)
      xa[ks] = *(const bf16x8*)(xrow + ks * 32);
    const short* wrow = w1bf + d * (MM1 * DD);
    #pragma unroll
    for (int mi = 0; mi < 2; ++mi) {
      const int m = (mtp + mi) * 16 + l15;
      f32x4 acc = {0.f, 0.f, 0.f, 0.f};
      #pragma unroll
      for (int ks = 0; ks < 4; ++ks) {
        bf16x8 wb = *(const bf16x8*)(wrow + m * DD + ks * 32 + g * 8);
        acc = __builtin_amdgcn_mfma_f32_16x16x32_bf16(xa[ks], wb, acc, 0, 0, 0);
      }
      const float cpre = b1s[d * MM1 + m];
      #pragma unroll
      for (int r = 0; r < 4; ++r) {
        const int bl = bt * 16 + g * 4 + r;
        sS[bl * 64 + ((m & ~7) ^ ((bl & 7) << 3)) + (m & 7)] =
            f2b(sigm_pre(acc[r], cpre));
      }
    }
  }
  __syncthreads();

  // ---------------- phase 2: k-outer (4 k per wave), 4 row-tiles inner -----
  float y1p[4] = {0, 0, 0, 0}, y2p[4] = {0, 0, 0, 0};

  #pragma unroll
  for (int kk = 0; kk < 4; ++kk) {
    const int k = wv * 4 + kk;
    // A-fragments (loop-invariant over rt): rows cp = k*32 + nh*16 + l15
    const short* ap = lc1T + (k * 32 + l15) * 64 + g * 8;
    const bf16x8 A00 = *(const bf16x8*)(ap);
    const bf16x8 A01 = *(const bf16x8*)(ap + 32);
    const bf16x8 A10 = *(const bf16x8*)(ap + 16 * 64);
    const bf16x8 A11 = *(const bf16x8*)(ap + 16 * 64 + 32);
    const f32x4 c40 = *(const f32x4*)&cS[k * 32 + g * 4];
    const f32x4 c41 = *(const f32x4*)&cS[k * 32 + 16 + g * 4];
    const f32x4 w40 = *(const f32x4*)&wSS[k * 32 + g * 4];
    const f32x4 w41 = *(const f32x4*)&wSS[k * 32 + 16 + g * 4];
    const float lb = lbq[k];

    #pragma unroll
    for (int rt = 0; rt < 4; ++rt) {
      const int b = rt * 16 + l15;
      const int bsw = (b & 7) << 3;
      const bf16x8 sa0 = *(const bf16x8*)&sS[b * 64 + ((g * 8) ^ bsw)];
      const bf16x8 sa1 = *(const bf16x8*)&sS[b * 64 + ((32 + g * 8) ^ bsw)];
      f32x4 a0 = {0.f, 0.f, 0.f, 0.f}, a1 = {0.f, 0.f, 0.f, 0.f};
      a0 = __builtin_amdgcn_mfma_f32_16x16x32_bf16(A00, sa0, a0, 0, 0, 0);
      a0 = __builtin_amdgcn_mfma_f32_16x16x32_bf16(A01, sa1, a0, 0, 0, 0);
      a1 = __builtin_amdgcn_mfma_f32_16x16x32_bf16(A10, sa0, a1, 0, 0, 0);
      a1 = __builtin_amdgcn_mfma_f32_16x16x32_bf16(A11, sa1, a1, 0, 0, 0);
      float v = lb;
      #pragma unroll
      for (int r = 0; r < 4; ++r) {
        v = fmaf(sigm_pre(a0[r], c40[r]), w40[r], v);
        v = fmaf(sigm_pre(a1[r], c41[r]), w41[r], v);
      }
      y1p[rt] = fmaf(v, betaS[k * 64 + rt * 16 + l15], y1p[rt]);
      y2p[rt] = fmaf(v, reconS[k * 64 + rt * 16 + l15], y2p[rt]);
    }
  }

  // ---------------- reduce: g-groups (shfl), waves (LDS) -------------------
  #pragma unroll
  for (int rt = 0; rt < 4; ++rt) {
    y1p[rt] += __shfl_xor(y1p[rt], 16, 64);
    y1p[rt] += __shfl_xor(y1p[rt], 32, 64);
    y2p[rt] += __shfl_xor(y2p[rt], 16, 64);
    y2p[rt] += __shfl_xor(y2p[rt], 32, 64);
  }
  if (g == 0) {
    #pragma unroll
    for (int rt = 0; rt < 4; ++rt) {
      yred[wv][rt * 16 + l15][0] = y1p[rt];
      yred[wv][rt * 16 + l15][1] = y2p[rt];
    }
  }
  __syncthreads();
  if (tid < 128) {
    const int bl = tid >> 1, o = tid & 1;
    float s = 0.f;
    #pragma unroll
    for (int w = 0; w < 8; ++w) s += yred[w][bl][o];
    const int b = bq * 64 + bl;
    out[o * (BB * DD) + b * DD + d] = s + betab[b];
  }
}

// ---------------------------------------------------------------------------
extern "C" void kernel_launch(void* const* d_in, const int* in_sizes, int n_in,
                              void* d_out, int out_size, void* d_ws, size_t ws_size,
                              hipStream_t stream) {
  const float* x     = (const float*)d_in[0];
  const float* W1p   = (const float*)d_in[1];
  const float* W1n   = (const float*)d_in[2];
  const float* b1p   = (const float*)d_in[3];
  const float* b1n   = (const float*)d_in[4];
  const float* lc1w  = (const float*)d_in[5];
  const float* lc1b  = (const float*)d_in[6];
  const float* lc2w  = (const float*)d_in[7];
  const float* lc2b  = (const float*)d_in[8];
  const float* betaw = (const float*)d_in[9];
  const float* betab = (const float*)d_in[10];
  const float* enc1w = (const float*)d_in[11];
  const float* enc1b = (const float*)d_in[12];
  const float* enc2w = (const float*)d_in[13];
  const float* enc2b = (const float*)d_in[14];
  const float* muw   = (const float*)d_in[15];
  const float* mub   = (const float*)d_in[16];
  const float* lvw   = (const float*)d_in[17];
  const float* lvb   = (const float*)d_in[18];
  const float* dec1w = (const float*)d_in[19];
  const float* dec1b = (const float*)d_in[20];
  const float* dec2w = (const float*)d_in[21];
  const float* dec2b = (const float*)d_in[22];
  const float* dec3w = (const float*)d_in[23];
  const float* dec3b = (const float*)d_in[24];
  const float* eps   = (const float*)d_in[25];

  float* out    = (float*)d_out;
  char*  ws     = (char*)d_ws;
  float* mu_out = out + BB * DD * 2;            // 65536
  float* lv_out = mu_out + BB * 32;             // 73728

  combo_kernel<<<dim3(1280), dim3(256), 0, stream>>>(
      x, W1p, W1n, b1p, b1n, lc1w, lc1b, lc2b, betaw,
      enc1w, enc1b, enc2w, enc2b, muw, mub, lvw, lvb,
      dec1w, dec1b, dec2w, dec2b, dec3w, dec3b, eps,
      ws, mu_out, lv_out);

  main_kernel<<<dim3(512), dim3(512), 0, stream>>>(
      lc2w, betab, (const char*)ws, out);
}